// Round 14
// baseline (237.806 us; speedup 1.0000x reference)
//
#include <hip/hip_runtime.h>
#include <stdint.h>
#include <math.h>

using short8 = __attribute__((ext_vector_type(8))) short;
using f32x4  = __attribute__((ext_vector_type(4))) float;

#define DEV __device__ __forceinline__
#define S_VMCNT(n) asm volatile("s_waitcnt vmcnt(" #n ")" ::: "memory")
#define S_LGKM(n)  asm volatile("s_waitcnt lgkmcnt(" #n ")" ::: "memory")
#define S_LGKM0()  asm volatile("s_waitcnt lgkmcnt(0)" ::: "memory")
#define SCHED0()   __builtin_amdgcn_sched_barrier(0)
#define SBAR()     __builtin_amdgcn_s_barrier()

DEV unsigned short f2bf(float f) {
    union { float f; unsigned u; } c; c.f = f;
    unsigned u = c.u;
    unsigned r = (u + 0x7FFFu + ((u >> 16) & 1u)) >> 16;
    return (unsigned short)r;
}

DEV float bf2f(unsigned short h) {
    union { unsigned u; float f; } c; c.u = ((unsigned)h) << 16;
    return c.f;
}

DEV void gld16(const unsigned short* g, unsigned short* l) {
    __builtin_amdgcn_global_load_lds(
        (const __attribute__((address_space(1))) void*)g,
        (__attribute__((address_space(3))) void*)l, 16, 0, 0);
}

DEV unsigned ldsaddr(unsigned short* p) {
    return (unsigned)(uintptr_t)(__attribute__((address_space(3))) unsigned short*)p;
}

DEV unsigned cvtpk(float lo, float hi) {
    unsigned r;
    asm("v_cvt_pk_bf16_f32 %0, %1, %2" : "=v"(r) : "v"(lo), "v"(hi));
    return r;
}

DEV uint2 tr16(unsigned addr) {
    uint2 r;
    asm volatile("ds_read_b64_tr_b16 %0, %1" : "=v"(r) : "v"(addr));
    return r;
}

// ---------------- prep: LN1 (+bf16 copy of x) fused with 4 weight transposes ----------------
__global__ __launch_bounds__(256) void k_prep(
    const float* __restrict__ x, const float* __restrict__ g,
    const float* __restrict__ b, unsigned short* __restrict__ h_out,
    unsigned short* __restrict__ xb,
    const float* __restrict__ w0, const float* __restrict__ w1,
    const float* __restrict__ w2, const float* __restrict__ w3,
    unsigned short* __restrict__ o0, unsigned short* __restrict__ o1,
    unsigned short* __restrict__ o2, unsigned short* __restrict__ o3)
{
    __shared__ float tile[32][33];
    __shared__ float red[8];
    int bid = blockIdx.x;
    int tid = threadIdx.x;

    if (bid < 8192) {
        int row = bid;
        const float* xr = x + (size_t)row * 768;
        float v0 = xr[tid], v1 = xr[tid + 256], v2 = xr[tid + 512];
        float s1 = v0 + v1 + v2;
        float s2 = v0 * v0 + v1 * v1 + v2 * v2;
#pragma unroll
        for (int off = 32; off >= 1; off >>= 1) {
            s1 += __shfl_down(s1, off);
            s2 += __shfl_down(s2, off);
        }
        int wid = tid >> 6, lane = tid & 63;
        if (lane == 0) { red[wid] = s1; red[4 + wid] = s2; }
        __syncthreads();
        s1 = red[0] + red[1] + red[2] + red[3];
        s2 = red[4] + red[5] + red[6] + red[7];
        float mu = s1 * (1.0f / 768.0f);
        float var = s2 * (1.0f / 768.0f) - mu * mu;
        float rs = rsqrtf(var + 1e-5f);
        unsigned short* orow = h_out + (size_t)row * 768;
        unsigned short* xrow = xb + (size_t)row * 768;
        orow[tid]       = f2bf((v0 - mu) * rs * g[tid]       + b[tid]);
        orow[tid + 256] = f2bf((v1 - mu) * rs * g[tid + 256] + b[tid + 256]);
        orow[tid + 512] = f2bf((v2 - mu) * rs * g[tid + 512] + b[tid + 512]);
        xrow[tid]       = f2bf(v0);
        xrow[tid + 256] = f2bf(v1);
        xrow[tid + 512] = f2bf(v2);
    } else {
        int idx = bid - 8192;
        const float* W; unsigned short* Wt; int N, n0, k0;
        if (idx < 1728) {
            W = w0; Wt = o0; N = 2304;
            n0 = (idx % 72) * 32; k0 = (idx / 72) * 32;
        } else {
            idx -= 1728;
            int z = idx / 576, r = idx % 576;
            W = (z == 0) ? w1 : (z == 1) ? w2 : w3;
            Wt = (z == 0) ? o1 : (z == 1) ? o2 : o3;
            N = 768;
            n0 = (r % 24) * 32; k0 = (r / 24) * 32;
        }
        int tx = tid & 31, ty = tid >> 5;
#pragma unroll
        for (int i = 0; i < 4; i++) {
            int k = k0 + ty + i * 8;
            tile[ty + i * 8][tx] = W[(size_t)k * N + n0 + tx];
        }
        __syncthreads();
#pragma unroll
        for (int i = 0; i < 4; i++) {
            int n = n0 + ty + i * 8;
            Wt[(size_t)n * 768 + k0 + tx] = f2bf(tile[tx][ty + i * 8]);
        }
    }
}

// ---------------- layernorm row(768) -> bf16; input bf16 ----------------
__global__ __launch_bounds__(256) void k_layernorm_bf(
    const unsigned short* __restrict__ xin, const float* __restrict__ g,
    const float* __restrict__ b, unsigned short* __restrict__ out)
{
    int row = blockIdx.x;
    int tid = threadIdx.x;
    const unsigned short* xr = xin + (size_t)row * 768;
    float v0 = bf2f(xr[tid]), v1 = bf2f(xr[tid + 256]), v2 = bf2f(xr[tid + 512]);
    float s1 = v0 + v1 + v2;
    float s2 = v0 * v0 + v1 * v1 + v2 * v2;
#pragma unroll
    for (int off = 32; off >= 1; off >>= 1) {
        s1 += __shfl_down(s1, off);
        s2 += __shfl_down(s2, off);
    }
    __shared__ float red[8];
    int wid = tid >> 6, lane = tid & 63;
    if (lane == 0) { red[wid] = s1; red[4 + wid] = s2; }
    __syncthreads();
    s1 = red[0] + red[1] + red[2] + red[3];
    s2 = red[4] + red[5] + red[6] + red[7];
    float mu = s1 * (1.0f / 768.0f);
    float var = s2 * (1.0f / 768.0f) - mu * mu;
    float rs = rsqrtf(var + 1e-5f);
    unsigned short* orow = out + (size_t)row * 768;
    orow[tid]       = f2bf((v0 - mu) * rs * g[tid]       + b[tid]);
    orow[tid + 256] = f2bf((v1 - mu) * rs * g[tid + 256] + b[tid + 256]);
    orow[tid + 512] = f2bf((v2 - mu) * rs * g[tid + 512] + b[tid + 512]);
}

// ---------------- GEMM (round-13, unchanged): BK=64, 2 LDS bufs, counted vmcnt ----
template<int EPI, int BN>
__global__ __launch_bounds__(BN == 128 ? 512 : 256) void k_gemm(
    const unsigned short* __restrict__ A, const unsigned short* __restrict__ Bt,
    const float* __restrict__ bias, const unsigned short* __restrict__ residH,
    float* __restrict__ outF, unsigned short* __restrict__ outH,
    unsigned short* __restrict__ qb, unsigned short* __restrict__ kb,
    unsigned short* __restrict__ vtb)
{
    constexpr int KK = 768, NK = 12;
    constexpr int MI = 2;
    constexpr int NJ = 4;
    __shared__ __align__(16) unsigned short As[2][128 * 64];
    __shared__ __align__(16) unsigned short Bs[2][BN * 64];

    int tid = threadIdx.x;
    int lane = tid & 63, wid = tid >> 6;

    int gy = gridDim.y;
    int nwg = 64 * gy;
    int bid = blockIdx.x + blockIdx.y * 64;
    int nid = (bid & 7) * (nwg >> 3) + (bid >> 3);
    int bx = nid / gy;
    int by = nid - bx * gy;
    int m0 = bx * 128, n0 = by * BN;

    int wr = (BN == 128) ? (wid >> 1) * 32 : wid * 32;
    int wc = (BN == 128) ? (wid & 1) * 64 : 0;
    int fr = lane & 15, fg = lane >> 4;
    int fr7 = fr & 7;

    f32x4 zero4 = {0.f, 0.f, 0.f, 0.f};
    f32x4 acc[MI][NJ];
#pragma unroll
    for (int mi = 0; mi < MI; mi++)
#pragma unroll
        for (int nj = 0; nj < NJ; nj++) acc[mi][nj] = zero4;

    int srow = tid >> 3;
    int schk = (tid & 7) ^ ((tid >> 3) & 7);
    const unsigned short* ga = A  + (size_t)(m0 + srow) * KK + schk * 8;
    const unsigned short* gb = Bt + (size_t)(n0 + srow) * KK + schk * 8;

    auto stage = [&](int kt, int s) {
        int ko = kt * 64;
        if constexpr (BN == 128) {
            gld16(ga + ko, As[s] + wid * 512);
            gld16(ga + (size_t)64 * KK + ko, As[s] + 4096 + wid * 512);
            gld16(gb + ko, Bs[s] + wid * 512);
            gld16(gb + (size_t)64 * KK + ko, Bs[s] + 4096 + wid * 512);
        } else {
#pragma unroll
            for (int i = 0; i < 4; i++)
                gld16(ga + (size_t)i * 32 * KK + ko, As[s] + i * 2048 + wid * 512);
#pragma unroll
            for (int i = 0; i < 2; i++)
                gld16(gb + (size_t)i * 32 * KK + ko, Bs[s] + i * 2048 + wid * 512);
        }
    };

    int aoff0 = (wr + fr) * 64;
    int boff0 = (wc + fr) * 64;

    stage(0, 0);

    for (int k = 0; k < NK; ++k) {
        if (k + 1 < NK) {
            stage(k + 1, (k + 1) & 1);
            if constexpr (BN == 128) { S_VMCNT(4); } else { S_VMCNT(6); }
        } else {
            S_VMCNT(0);
        }
        SCHED0(); SBAR(); SCHED0();

        const unsigned short* Ac = As[k & 1];
        const unsigned short* Bc = Bs[k & 1];
#pragma unroll
        for (int kk = 0; kk < 2; ++kk) {
            int off = (((kk << 2) | fg) ^ fr7) * 8;
            short8 af[MI], bfv[NJ];
#pragma unroll
            for (int mi = 0; mi < MI; mi++)
                af[mi] = *(const short8*)(Ac + aoff0 + mi * 1024 + off);
#pragma unroll
            for (int nj = 0; nj < NJ; nj++)
                bfv[nj] = *(const short8*)(Bc + boff0 + nj * 1024 + off);
#pragma unroll
            for (int mi = 0; mi < MI; mi++)
#pragma unroll
                for (int nj = 0; nj < NJ; nj++)
                    acc[mi][nj] = __builtin_amdgcn_mfma_f32_16x16x32_bf16(
                        af[mi], bfv[nj], acc[mi][nj], 0, 0, 0);
        }
        SCHED0(); SBAR(); SCHED0();
    }

    if (EPI == 0 && n0 >= 1536) {
        unsigned short* Ct = &As[0][0];
#pragma unroll
        for (int mi = 0; mi < MI; mi++) {
#pragma unroll
            for (int nj = 0; nj < NJ; nj++) {
                int row = wc + nj * 16 + fr;
                int colb = wr + mi * 16 + fg * 4;
                int ch = (colb >> 3) ^ (row & 15);
                uint2 w;
                w.x = cvtpk(acc[mi][nj][0], acc[mi][nj][1]);
                w.y = cvtpk(acc[mi][nj][2], acc[mi][nj][3]);
                *(uint2*)(Ct + row * 128 + ch * 8 + (colb & 7)) = w;
            }
        }
        __syncthreads();
        int r = tid >> 2;
        int h0 = (n0 - 1536) >> 6;
        int bb = m0 >> 10;
        int nbase = m0 & 1023;
        size_t vbase = ((size_t)(bb * 12 + h0 + (r >> 6)) << 16)
                     + (size_t)(r & 63) * 1024 + nbase;
#pragma unroll
        for (int j = 0; j < 4; j++) {
            int c = (tid & 3) * 4 + j;
            int ch = c ^ (r & 15);
            uint4 v4 = *(const uint4*)(Ct + r * 128 + ch * 8);
            *(uint4*)(vtb + vbase + c * 8) = v4;
        }
        return;
    }

#pragma unroll
    for (int mi = 0; mi < MI; mi++) {
#pragma unroll
        for (int nj = 0; nj < NJ; nj++) {
#pragma unroll
            for (int i = 0; i < 4; i++) {
                int grow = m0 + wr + mi * 16 + fg * 4 + i;
                int gcol = n0 + wc + nj * 16 + fr;
                float v = acc[mi][nj][i];
                if (EPI == 0) {
                    int part = gcol / 768;
                    int wi = gcol - part * 768;
                    int head = wi >> 6, d = wi & 63;
                    int bb = grow >> 10, n = grow & 1023;
                    size_t base = ((size_t)(bb * 12 + head)) << 16;
                    unsigned short bv = f2bf(v);
                    if (part == 0) qb[base + (size_t)n * 64 + d] = bv;
                    else           kb[base + (size_t)n * 64 + d] = bv;
                } else if (EPI == 1) {
                    size_t idx = (size_t)grow * 768 + gcol;
                    outH[idx] = f2bf(v + bias[gcol] + bf2f(residH[idx]));
                } else if (EPI == 2) {
                    float t = v + bias[gcol];
                    outH[(size_t)grow * 768 + gcol] =
                        f2bf(0.5f * t * (1.0f + erff(t * 0.70710678118f)));
                } else {
                    size_t idx = (size_t)grow * 768 + gcol;
                    outF[idx] = v + bias[gcol] + bf2f(residH[idx]);
                }
            }
        }
    }
}

// ---------------- flash attention: V direct-from-global, K 2-buf LDS ----------------
// LDS = K(2x8KB) + PT(16KB) + mask(4KB) = 36KB -> 3-4 blocks/CU.
// V is L2-resident; PV B-fragments are contiguous 16B global loads
// (V[d=df*16+fr][key=fg*8+j]) issued at step-top, covered by QK+softmax,
// drained with counted vmcnt(1) (K-stage stays in flight). One barrier/step.
// K 2-buf WAR-safe: buf (kc+1)&1's last readers finished before SBAR(kc).
__global__ __launch_bounds__(512) void k_attn(
    const unsigned short* __restrict__ Q, const unsigned short* __restrict__ Kk,
    const unsigned short* __restrict__ Vt, const int* __restrict__ mask,
    unsigned short* __restrict__ O)
{
    __shared__ __align__(16) unsigned short KsA[2 * 4096];
    __shared__ __align__(16) unsigned short PT[8 * 1024];
    __shared__ float mskf[1024];

    int tid = threadIdx.x, lane = tid & 63, wid = tid >> 6;
    int bid = blockIdx.x + blockIdx.y * 8;
    int nid = (bid & 7) * 96 + (bid >> 3);
    int qt = nid & 7;
    int bh = nid >> 3;
    int b = bh / 12;
    int hh = bh - b * 12;
    int fr = lane & 15, fg = lane >> 4;

    const unsigned short* qg = Q  + ((size_t)bh << 16);
    const unsigned short* kg = Kk + ((size_t)bh << 16);
    const unsigned short* vg = Vt + ((size_t)bh << 16);

    for (int i = tid; i < 1024; i += 512)
        mskf[i] = mask[b * 1024 + i] ? 1.f : 0.f;

    short8 qf[2];
    {
        const unsigned short* qp = qg + (size_t)(qt * 128 + wid * 16 + fr) * 64 + fg * 8;
        qf[0] = *(const short8*)(qp);
        qf[1] = *(const short8*)(qp + 32);
    }

    // K staging: 512 threads cover 64 rows x 64 d in one gld16
    int srow = tid >> 3;
    int schk = (tid & 7) ^ ((tid >> 3) & 7);
    const unsigned short* kgp = kg + (size_t)srow * 64 + schk * 8;

    auto stageK = [&](int kn, int s) {
        gld16(kgp + (size_t)(kn * 64) * 64, &KsA[s * 4096] + wid * 512);
    };

    // V direct: lane base for V[d = df*16+fr][key-chunk offsets]
    const unsigned short* vbase = vg + (size_t)fr * 1024 + fg * 8;

    stageK(0, 0);
    __syncthreads();   // mskf + K(0) drained (prologue only)

    f32x4 zero4 = {0.f, 0.f, 0.f, 0.f};
    f32x4 oacc[4];
    f32x4 lacc = zero4;
#pragma unroll
    for (int df = 0; df < 4; df++) oacc[df] = zero4;

    short8 ones8;
#pragma unroll
    for (int j = 0; j < 8; j++) ones8[j] = (short)0x3F80;

    const float SC = 0.125f * 1.44269504f;

    unsigned short* pw = &PT[wid * 1024];
    unsigned trbase = ldsaddr(pw) + fg * 256 + fr * 2;

    int pos0 = fg ^ (fr & 7);
    int pos1 = (fg + 4) ^ (fr & 7);

#pragma unroll
    for (int kc = 0; kc < 16; ++kc) {
        S_VMCNT(0);               // K(kc) staged (issued a full step earlier)
        SCHED0(); SBAR(); SCHED0();

        // V(kc-1) fragment loads direct from global (L2-hit), issued early
        short8 vb0[4], vb1[4];
        if (kc > 0) {
            const unsigned short* vc = vbase + (kc - 1) * 64;
#pragma unroll
            for (int df = 0; df < 4; ++df) {
                vb0[df] = *(const short8*)(vc + (size_t)df * 16384);
                vb1[df] = *(const short8*)(vc + (size_t)df * 16384 + 32);
            }
            SCHED0();
        }
        if (kc < 15) { stageK(kc + 1, (kc + 1) & 1); SCHED0(); }

        const unsigned short* Kc = &KsA[(kc & 1) * 4096];
        short8 kb0[4], kb1[4];
#pragma unroll
        for (int nf = 0; nf < 4; ++nf) {
            int row = nf * 16 + fr;
            kb0[nf] = *(const short8*)(Kc + row * 64 + pos0 * 8);
            kb1[nf] = *(const short8*)(Kc + row * 64 + pos1 * 8);
        }
        SCHED0();

        f32x4 s[4];
        if (kc > 0) {
            S_LGKM(8);            // P-writes(kc-1) retired (8 K-reads newest)
            uint2 r00 = tr16(trbase);
            uint2 r01 = tr16(trbase + 128);
            uint2 r10 = tr16(trbase + 1024);
            uint2 r11 = tr16(trbase + 1024 + 128);
            S_LGKM(4);            // K frags done; tr16 still flying
            SCHED0();
            __builtin_amdgcn_s_setprio(1);
#pragma unroll
            for (int nf = 0; nf < 4; ++nf) {
                f32x4 a = zero4;
                a = __builtin_amdgcn_mfma_f32_16x16x32_bf16(qf[0], kb0[nf], a, 0, 0, 0);
                a = __builtin_amdgcn_mfma_f32_16x16x32_bf16(qf[1], kb1[nf], a, 0, 0, 0);
                s[nf] = a;
            }
            __builtin_amdgcn_s_setprio(0);

            union { unsigned u[4]; short8 s8; } pa0, pa1;
            pa0.u[0] = r00.x; pa0.u[1] = r00.y; pa0.u[2] = r01.x; pa0.u[3] = r01.y;
            pa1.u[0] = r10.x; pa1.u[1] = r10.y; pa1.u[2] = r11.x; pa1.u[3] = r11.y;

            // softmax(kc) while V loads + tr16 fly
            uint2 w[4];
#pragma unroll
            for (int nf = 0; nf < 4; nf++) {
                float mk = mskf[kc * 64 + nf * 16 + fr];
                float p0 = __builtin_amdgcn_exp2f(s[nf][0] * SC) * mk;
                float p1 = __builtin_amdgcn_exp2f(s[nf][1] * SC) * mk;
                float p2 = __builtin_amdgcn_exp2f(s[nf][2] * SC) * mk;
                float p3 = __builtin_amdgcn_exp2f(s[nf][3] * SC) * mk;
                w[nf].x = cvtpk(p0, p1); w[nf].y = cvtpk(p2, p3);
            }

            if (kc < 15) { S_VMCNT(1); } else { S_VMCNT(0); }   // V done; K-stage may fly
            S_LGKM0();                                          // tr16 done
            SCHED0();
            __builtin_amdgcn_s_setprio(1);
#pragma unroll
            for (int df = 0; df < 4; df++) {
                oacc[df] = __builtin_amdgcn_mfma_f32_16x16x32_bf16(pa0.s8, vb0[df], oacc[df], 0, 0, 0);
                oacc[df] = __builtin_amdgcn_mfma_f32_16x16x32_bf16(pa1.s8, vb1[df], oacc[df], 0, 0, 0);
            }
            lacc = __builtin_amdgcn_mfma_f32_16x16x32_bf16(pa0.s8, ones8, lacc, 0, 0, 0);
            lacc = __builtin_amdgcn_mfma_f32_16x16x32_bf16(pa1.s8, ones8, lacc, 0, 0, 0);
            __builtin_amdgcn_s_setprio(0);

            // P(kc) write (tr16 of P(kc-1) retired: same-wave DS FIFO + lgkm0)
#pragma unroll
            for (int nf = 0; nf < 4; nf++)
                *(uint2*)(pw + (nf * 16 + fr) * 16 + fg * 4) = w[nf];
        } else {
            S_LGKM0();
            SCHED0();
            __builtin_amdgcn_s_setprio(1);
#pragma unroll
            for (int nf = 0; nf < 4; ++nf) {
                f32x4 a = zero4;
                a = __builtin_amdgcn_mfma_f32_16x16x32_bf16(qf[0], kb0[nf], a, 0, 0, 0);
                a = __builtin_amdgcn_mfma_f32_16x16x32_bf16(qf[1], kb1[nf], a, 0, 0, 0);
                s[nf] = a;
            }
            __builtin_amdgcn_s_setprio(0);
#pragma unroll
            for (int nf = 0; nf < 4; nf++) {
                float mk = mskf[nf * 16 + fr];
                float p0 = __builtin_amdgcn_exp2f(s[nf][0] * SC) * mk;
                float p1 = __builtin_amdgcn_exp2f(s[nf][1] * SC) * mk;
                float p2 = __builtin_amdgcn_exp2f(s[nf][2] * SC) * mk;
                float p3 = __builtin_amdgcn_exp2f(s[nf][3] * SC) * mk;
                uint2 w0; w0.x = cvtpk(p0, p1); w0.y = cvtpk(p2, p3);
                *(uint2*)(pw + (nf * 16 + fr) * 16 + fg * 4) = w0;
            }
        }
    }

    // ---- epilogue: PV(15)
    {
        short8 vb0[4], vb1[4];
        const unsigned short* vc = vbase + 15 * 64;
#pragma unroll
        for (int df = 0; df < 4; ++df) {
            vb0[df] = *(const short8*)(vc + (size_t)df * 16384);
            vb1[df] = *(const short8*)(vc + (size_t)df * 16384 + 32);
        }
        uint2 r00 = tr16(trbase);
        uint2 r01 = tr16(trbase + 128);
        uint2 r10 = tr16(trbase + 1024);
        uint2 r11 = tr16(trbase + 1024 + 128);
        S_VMCNT(0); S_LGKM0(); SCHED0();
        union { unsigned u[4]; short8 s8; } pa0, pa1;
        pa0.u[0] = r00.x; pa0.u[1] = r00.y; pa0.u[2] = r01.x; pa0.u[3] = r01.y;
        pa1.u[0] = r10.x; pa1.u[1] = r10.y; pa1.u[2] = r11.x; pa1.u[3] = r11.y;
#pragma unroll
        for (int df = 0; df < 4; df++) {
            oacc[df] = __builtin_amdgcn_mfma_f32_16x16x32_bf16(pa0.s8, vb0[df], oacc[df], 0, 0, 0);
            oacc[df] = __builtin_amdgcn_mfma_f32_16x16x32_bf16(pa1.s8, vb1[df], oacc[df], 0, 0, 0);
        }
        lacc = __builtin_amdgcn_mfma_f32_16x16x32_bf16(pa0.s8, ones8, lacc, 0, 0, 0);
        lacc = __builtin_amdgcn_mfma_f32_16x16x32_bf16(pa1.s8, ones8, lacc, 0, 0, 0);
    }

#pragma unroll
    for (int i = 0; i < 4; i++) {
        float inv = 1.0f / fmaxf(lacc[i], 1e-30f);
        size_t rowbase = ((size_t)(b * 1024 + qt * 128 + wid * 16 + fg * 4 + i)) * 768
                         + hh * 64 + fr;
#pragma unroll
        for (int df = 0; df < 4; df++)
            O[rowbase + df * 16] = f2bf(oacc[df][i] * inv);
    }
}

// ---------------- launch ----------------
extern "C" void kernel_launch(void* const* d_in, const int* in_sizes, int n_in,
                              void* d_out, int out_size, void* d_ws, size_t ws_size,
                              hipStream_t stream)
{
    const float* x      = (const float*)d_in[0];
    const int*   mask   = (const int*)d_in[1];
    const float* g1     = (const float*)d_in[2];
    const float* b1     = (const float*)d_in[3];
    const float* w_qkv  = (const float*)d_in[4];
    const float* w_proj = (const float*)d_in[5];
    const float* b_proj = (const float*)d_in[6];
    const float* g2     = (const float*)d_in[7];
    const float* b2     = (const float*)d_in[8];
    const float* w_fc1  = (const float*)d_in[9];
    const float* b_fc1  = (const float*)d_in[10];
    const float* w_fc2  = (const float*)d_in[11];
    const float* b_fc2  = (const float*)d_in[12];
    float* out = (float*)d_out;

    char* ws = (char*)d_ws;
    unsigned short* wqkv_t  = (unsigned short*)(ws + 0);
    unsigned short* wproj_t = (unsigned short*)(ws + 3538944);
    unsigned short* wfc1_t  = (unsigned short*)(ws + 4718592);
    unsigned short* wfc2_t  = (unsigned short*)(ws + 5898240);
    unsigned short* bufA    = (unsigned short*)(ws + 7077888);   // h / h2
    unsigned short* bufB    = (unsigned short*)(ws + 19660800);  // o / gelu-out
    unsigned short* qb      = (unsigned short*)(ws + 32243712);
    unsigned short* kb      = (unsigned short*)(ws + 44826624);
    unsigned short* vtb     = (unsigned short*)(ws + 57409536);
    unsigned short* x1b     = (unsigned short*)(ws + 69992448);  // bf16 residual trunk
    unsigned short* xb      = (unsigned short*)(ws + 82575360);  // bf16 copy of x
    // total = 95,158,272 bytes

    k_prep<<<8192 + 3456, 256, 0, stream>>>(x, g1, b1, bufA, xb,
        w_qkv, w_proj, w_fc1, w_fc2, wqkv_t, wproj_t, wfc1_t, wfc2_t);

    k_gemm<0, 128><<<dim3(64, 18), 512, 0, stream>>>(bufA, wqkv_t,
        nullptr, nullptr, nullptr, nullptr, qb, kb, vtb);

    k_attn<<<dim3(8, 96), 512, 0, stream>>>(qb, kb, vtb, mask, bufB);

    k_gemm<1, 64><<<dim3(64, 12), 256, 0, stream>>>(bufB, wproj_t,
        b_proj, xb, nullptr, x1b, nullptr, nullptr, nullptr);

    k_layernorm_bf<<<8192, 256, 0, stream>>>(x1b, g2, b2, bufA);

    k_gemm<2, 64><<<dim3(64, 12), 256, 0, stream>>>(bufA, wfc1_t,
        b_fc1, nullptr, nullptr, bufB, nullptr, nullptr, nullptr);

    k_gemm<3, 64><<<dim3(64, 12), 256, 0, stream>>>(bufB, wfc2_t,
        b_fc2, x1b, out, nullptr, nullptr, nullptr, nullptr);
}

// Round 15
// 159.727 us; speedup vs baseline: 1.4888x; 1.4888x over previous
//
#include <hip/hip_runtime.h>
#include <stdint.h>
#include <math.h>

using short8 = __attribute__((ext_vector_type(8))) short;
using f32x4  = __attribute__((ext_vector_type(4))) float;
using f32x16 = __attribute__((ext_vector_type(16))) float;

#define DEV __device__ __forceinline__
#define S_VMCNT(n) asm volatile("s_waitcnt vmcnt(" #n ")" ::: "memory")
#define SCHED0()   __builtin_amdgcn_sched_barrier(0)
#define SBAR()     __builtin_amdgcn_s_barrier()

DEV unsigned short f2bf(float f) {
    union { float f; unsigned u; } c; c.f = f;
    unsigned u = c.u;
    unsigned r = (u + 0x7FFFu + ((u >> 16) & 1u)) >> 16;
    return (unsigned short)r;
}

DEV float bf2f(unsigned short h) {
    union { unsigned u; float f; } c; c.u = ((unsigned)h) << 16;
    return c.f;
}

DEV void gld16(const unsigned short* g, unsigned short* l) {
    __builtin_amdgcn_global_load_lds(
        (const __attribute__((address_space(1))) void*)g,
        (__attribute__((address_space(3))) void*)l, 16, 0, 0);
}

DEV unsigned cvtpk(float lo, float hi) {
    unsigned r;
    asm("v_cvt_pk_bf16_f32 %0, %1, %2" : "=v"(r) : "v"(lo), "v"(hi));
    return r;
}

// ---------------- prep: LN1 (+bf16 copy of x) fused with 4 weight transposes ----------------
__global__ __launch_bounds__(256) void k_prep(
    const float* __restrict__ x, const float* __restrict__ g,
    const float* __restrict__ b, unsigned short* __restrict__ h_out,
    unsigned short* __restrict__ xb,
    const float* __restrict__ w0, const float* __restrict__ w1,
    const float* __restrict__ w2, const float* __restrict__ w3,
    unsigned short* __restrict__ o0, unsigned short* __restrict__ o1,
    unsigned short* __restrict__ o2, unsigned short* __restrict__ o3)
{
    __shared__ float tile[32][33];
    __shared__ float red[8];
    int bid = blockIdx.x;
    int tid = threadIdx.x;

    if (bid < 8192) {
        int row = bid;
        const float* xr = x + (size_t)row * 768;
        float v0 = xr[tid], v1 = xr[tid + 256], v2 = xr[tid + 512];
        float s1 = v0 + v1 + v2;
        float s2 = v0 * v0 + v1 * v1 + v2 * v2;
#pragma unroll
        for (int off = 32; off >= 1; off >>= 1) {
            s1 += __shfl_down(s1, off);
            s2 += __shfl_down(s2, off);
        }
        int wid = tid >> 6, lane = tid & 63;
        if (lane == 0) { red[wid] = s1; red[4 + wid] = s2; }
        __syncthreads();
        s1 = red[0] + red[1] + red[2] + red[3];
        s2 = red[4] + red[5] + red[6] + red[7];
        float mu = s1 * (1.0f / 768.0f);
        float var = s2 * (1.0f / 768.0f) - mu * mu;
        float rs = rsqrtf(var + 1e-5f);
        unsigned short* orow = h_out + (size_t)row * 768;
        unsigned short* xrow = xb + (size_t)row * 768;
        orow[tid]       = f2bf((v0 - mu) * rs * g[tid]       + b[tid]);
        orow[tid + 256] = f2bf((v1 - mu) * rs * g[tid + 256] + b[tid + 256]);
        orow[tid + 512] = f2bf((v2 - mu) * rs * g[tid + 512] + b[tid + 512]);
        xrow[tid]       = f2bf(v0);
        xrow[tid + 256] = f2bf(v1);
        xrow[tid + 512] = f2bf(v2);
    } else {
        int idx = bid - 8192;
        const float* W; unsigned short* Wt; int N, n0, k0;
        if (idx < 1728) {
            W = w0; Wt = o0; N = 2304;
            n0 = (idx % 72) * 32; k0 = (idx / 72) * 32;
        } else {
            idx -= 1728;
            int z = idx / 576, r = idx % 576;
            W = (z == 0) ? w1 : (z == 1) ? w2 : w3;
            Wt = (z == 0) ? o1 : (z == 1) ? o2 : o3;
            N = 768;
            n0 = (r % 24) * 32; k0 = (r / 24) * 32;
        }
        int tx = tid & 31, ty = tid >> 5;
#pragma unroll
        for (int i = 0; i < 4; i++) {
            int k = k0 + ty + i * 8;
            tile[ty + i * 8][tx] = W[(size_t)k * N + n0 + tx];
        }
        __syncthreads();
#pragma unroll
        for (int i = 0; i < 4; i++) {
            int n = n0 + ty + i * 8;
            Wt[(size_t)n * 768 + k0 + tx] = f2bf(tile[tx][ty + i * 8]);
        }
    }
}

// ---------------- layernorm row(768) -> bf16; input bf16 ----------------
__global__ __launch_bounds__(256) void k_layernorm_bf(
    const unsigned short* __restrict__ xin, const float* __restrict__ g,
    const float* __restrict__ b, unsigned short* __restrict__ out)
{
    int row = blockIdx.x;
    int tid = threadIdx.x;
    const unsigned short* xr = xin + (size_t)row * 768;
    float v0 = bf2f(xr[tid]), v1 = bf2f(xr[tid + 256]), v2 = bf2f(xr[tid + 512]);
    float s1 = v0 + v1 + v2;
    float s2 = v0 * v0 + v1 * v1 + v2 * v2;
#pragma unroll
    for (int off = 32; off >= 1; off >>= 1) {
        s1 += __shfl_down(s1, off);
        s2 += __shfl_down(s2, off);
    }
    __shared__ float red[8];
    int wid = tid >> 6, lane = tid & 63;
    if (lane == 0) { red[wid] = s1; red[4 + wid] = s2; }
    __syncthreads();
    s1 = red[0] + red[1] + red[2] + red[3];
    s2 = red[4] + red[5] + red[6] + red[7];
    float mu = s1 * (1.0f / 768.0f);
    float var = s2 * (1.0f / 768.0f) - mu * mu;
    float rs = rsqrtf(var + 1e-5f);
    unsigned short* orow = out + (size_t)row * 768;
    orow[tid]       = f2bf((v0 - mu) * rs * g[tid]       + b[tid]);
    orow[tid + 256] = f2bf((v1 - mu) * rs * g[tid + 256] + b[tid + 256]);
    orow[tid + 512] = f2bf((v2 - mu) * rs * g[tid + 512] + b[tid + 512]);
}

// ---------------- GEMM (round-13, unchanged): BK=64, 2 LDS bufs, counted vmcnt ----
template<int EPI, int BN>
__global__ __launch_bounds__(BN == 128 ? 512 : 256) void k_gemm(
    const unsigned short* __restrict__ A, const unsigned short* __restrict__ Bt,
    const float* __restrict__ bias, const unsigned short* __restrict__ residH,
    float* __restrict__ outF, unsigned short* __restrict__ outH,
    unsigned short* __restrict__ qb, unsigned short* __restrict__ kb,
    unsigned short* __restrict__ vtb)
{
    constexpr int KK = 768, NK = 12;
    constexpr int MI = 2;
    constexpr int NJ = 4;
    __shared__ __align__(16) unsigned short As[2][128 * 64];
    __shared__ __align__(16) unsigned short Bs[2][BN * 64];

    int tid = threadIdx.x;
    int lane = tid & 63, wid = tid >> 6;

    int gy = gridDim.y;
    int nwg = 64 * gy;
    int bid = blockIdx.x + blockIdx.y * 64;
    int nid = (bid & 7) * (nwg >> 3) + (bid >> 3);
    int bx = nid / gy;
    int by = nid - bx * gy;
    int m0 = bx * 128, n0 = by * BN;

    int wr = (BN == 128) ? (wid >> 1) * 32 : wid * 32;
    int wc = (BN == 128) ? (wid & 1) * 64 : 0;
    int fr = lane & 15, fg = lane >> 4;
    int fr7 = fr & 7;

    f32x4 zero4 = {0.f, 0.f, 0.f, 0.f};
    f32x4 acc[MI][NJ];
#pragma unroll
    for (int mi = 0; mi < MI; mi++)
#pragma unroll
        for (int nj = 0; nj < NJ; nj++) acc[mi][nj] = zero4;

    int srow = tid >> 3;
    int schk = (tid & 7) ^ ((tid >> 3) & 7);
    const unsigned short* ga = A  + (size_t)(m0 + srow) * KK + schk * 8;
    const unsigned short* gb = Bt + (size_t)(n0 + srow) * KK + schk * 8;

    auto stage = [&](int kt, int s) {
        int ko = kt * 64;
        if constexpr (BN == 128) {
            gld16(ga + ko, As[s] + wid * 512);
            gld16(ga + (size_t)64 * KK + ko, As[s] + 4096 + wid * 512);
            gld16(gb + ko, Bs[s] + wid * 512);
            gld16(gb + (size_t)64 * KK + ko, Bs[s] + 4096 + wid * 512);
        } else {
#pragma unroll
            for (int i = 0; i < 4; i++)
                gld16(ga + (size_t)i * 32 * KK + ko, As[s] + i * 2048 + wid * 512);
#pragma unroll
            for (int i = 0; i < 2; i++)
                gld16(gb + (size_t)i * 32 * KK + ko, Bs[s] + i * 2048 + wid * 512);
        }
    };

    int aoff0 = (wr + fr) * 64;
    int boff0 = (wc + fr) * 64;

    stage(0, 0);

    for (int k = 0; k < NK; ++k) {
        if (k + 1 < NK) {
            stage(k + 1, (k + 1) & 1);
            if constexpr (BN == 128) { S_VMCNT(4); } else { S_VMCNT(6); }
        } else {
            S_VMCNT(0);
        }
        SCHED0(); SBAR(); SCHED0();

        const unsigned short* Ac = As[k & 1];
        const unsigned short* Bc = Bs[k & 1];
#pragma unroll
        for (int kk = 0; kk < 2; ++kk) {
            int off = (((kk << 2) | fg) ^ fr7) * 8;
            short8 af[MI], bfv[NJ];
#pragma unroll
            for (int mi = 0; mi < MI; mi++)
                af[mi] = *(const short8*)(Ac + aoff0 + mi * 1024 + off);
#pragma unroll
            for (int nj = 0; nj < NJ; nj++)
                bfv[nj] = *(const short8*)(Bc + boff0 + nj * 1024 + off);
#pragma unroll
            for (int mi = 0; mi < MI; mi++)
#pragma unroll
                for (int nj = 0; nj < NJ; nj++)
                    acc[mi][nj] = __builtin_amdgcn_mfma_f32_16x16x32_bf16(
                        af[mi], bfv[nj], acc[mi][nj], 0, 0, 0);
        }
        SCHED0(); SBAR(); SCHED0();
    }

    if (EPI == 0 && n0 >= 1536) {
        unsigned short* Ct = &As[0][0];
#pragma unroll
        for (int mi = 0; mi < MI; mi++) {
#pragma unroll
            for (int nj = 0; nj < NJ; nj++) {
                int row = wc + nj * 16 + fr;
                int colb = wr + mi * 16 + fg * 4;
                int ch = (colb >> 3) ^ (row & 15);
                uint2 w;
                w.x = cvtpk(acc[mi][nj][0], acc[mi][nj][1]);
                w.y = cvtpk(acc[mi][nj][2], acc[mi][nj][3]);
                *(uint2*)(Ct + row * 128 + ch * 8 + (colb & 7)) = w;
            }
        }
        __syncthreads();
        int r = tid >> 2;
        int h0 = (n0 - 1536) >> 6;
        int bb = m0 >> 10;
        int nbase = m0 & 1023;
        size_t vbase = ((size_t)(bb * 12 + h0 + (r >> 6)) << 16)
                     + (size_t)(r & 63) * 1024 + nbase;
#pragma unroll
        for (int j = 0; j < 4; j++) {
            int c = (tid & 3) * 4 + j;
            int ch = c ^ (r & 15);
            uint4 v4 = *(const uint4*)(Ct + r * 128 + ch * 8);
            *(uint4*)(vtb + vbase + c * 8) = v4;
        }
        return;
    }

#pragma unroll
    for (int mi = 0; mi < MI; mi++) {
#pragma unroll
        for (int nj = 0; nj < NJ; nj++) {
#pragma unroll
            for (int i = 0; i < 4; i++) {
                int grow = m0 + wr + mi * 16 + fg * 4 + i;
                int gcol = n0 + wc + nj * 16 + fr;
                float v = acc[mi][nj][i];
                if (EPI == 0) {
                    int part = gcol / 768;
                    int wi = gcol - part * 768;
                    int head = wi >> 6, d = wi & 63;
                    int bb = grow >> 10, n = grow & 1023;
                    size_t base = ((size_t)(bb * 12 + head)) << 16;
                    unsigned short bv = f2bf(v);
                    if (part == 0) qb[base + (size_t)n * 64 + d] = bv;
                    else           kb[base + (size_t)n * 64 + d] = bv;
                } else if (EPI == 1) {
                    size_t idx = (size_t)grow * 768 + gcol;
                    outH[idx] = f2bf(v + bias[gcol] + bf2f(residH[idx]));
                } else if (EPI == 2) {
                    float t = v + bias[gcol];
                    outH[(size_t)grow * 768 + gcol] =
                        f2bf(0.5f * t * (1.0f + erff(t * 0.70710678118f)));
                } else {
                    size_t idx = (size_t)grow * 768 + gcol;
                    outF[idx] = v + bias[gcol] + bf2f(residH[idx]);
                }
            }
        }
    }
}

// ---------------- flash attention: 32x32 MFMA, in-register softmax (T12) ----------------
// 4 waves x 32 q-rows = 128 q/block; grid (8,96)=768 blocks; LDS 52KB -> 3 blocks/CU.
// Swapped QK: S^T = mfma32(A=K, B=Q) -> lane(c=lane&31,h=lane>>5) holds
// S[key=(reg&3)+8*(reg>>2)+4h + kf*32][q=c]. P=exp2(s*SC)*mask in-register;
// PV A-fragments via cvt_pk + v_permlane32_swap (word mapping verified by hand).
// No PT LDS, no tr16. K/V 3-buf, stage-after-barrier, one barrier/step.
__global__ __launch_bounds__(256) void k_attn(
    const unsigned short* __restrict__ Q, const unsigned short* __restrict__ Kk,
    const unsigned short* __restrict__ Vt, const int* __restrict__ mask,
    unsigned short* __restrict__ O)
{
    __shared__ __align__(16) unsigned short KsA[3 * 4096];
    __shared__ __align__(16) unsigned short VsA[3 * 4096];
    __shared__ __align__(16) float mskf[1024];

    int tid = threadIdx.x, lane = tid & 63, wid = tid >> 6;   // wid 0..3
    int bid = blockIdx.x + blockIdx.y * 8;
    int nid = (bid & 7) * 96 + (bid >> 3);
    int qt = nid & 7;          // 8 q-tiles of 128 rows
    int bh = nid >> 3;
    int b = bh / 12;
    int hh = bh - b * 12;
    int c = lane & 31, h = lane >> 5;

    const unsigned short* qg = Q  + ((size_t)bh << 16);
    const unsigned short* kg = Kk + ((size_t)bh << 16);
    const unsigned short* vg = Vt + ((size_t)bh << 16);

    for (int i = tid; i < 1024; i += 256)
        mskf[i] = mask[b * 1024 + i] ? 1.f : 0.f;

    // Q B-fragments: qf[ks] = Q[q=qt*128+wid*32+c][ks*16 + h*8 .. +8]
    short8 qf[4];
    {
        const unsigned short* qp = qg + (size_t)(qt * 128 + wid * 32 + c) * 64 + h * 8;
#pragma unroll
        for (int ks = 0; ks < 4; ks++)
            qf[ks] = *(const short8*)(qp + ks * 16);
    }

    // staging: 256 thr, srow=tid>>3 covers 32 rows/issue; 2 issues per 64-row tile
    int srow = tid >> 3;
    int schk = (tid & 7) ^ (srow & 7);
    const unsigned short* kgp = kg + (size_t)srow * 64 + schk * 8;
    const unsigned short* vgp = vg + (size_t)srow * 1024 + schk * 8;

    auto stage = [&](int kn, int s) {
        unsigned short* Kd = &KsA[s * 4096];
        unsigned short* Vd = &VsA[s * 4096];
        gld16(kgp + (size_t)(kn * 64) * 64, Kd + wid * 512);
        gld16(kgp + (size_t)(kn * 64 + 32) * 64, Kd + 2048 + wid * 512);
        gld16(vgp + kn * 64, Vd + wid * 512);
        gld16(vgp + 32 * 1024 + kn * 64, Vd + 2048 + wid * 512);
    };

    stage(0, 0);
    __syncthreads();   // mskf + stage(0) drained (prologue only)

    f32x16 oacc0, oacc1, lacc;
#pragma unroll
    for (int i = 0; i < 16; i++) { oacc0[i] = 0.f; oacc1[i] = 0.f; lacc[i] = 0.f; }

    short8 ones8;
#pragma unroll
    for (int j = 0; j < 8; j++) ones8[j] = (short)0x3F80;   // bf16 1.0

    const float SC = 0.125f * 1.44269504f;   // scale * log2(e)
    int c7 = c & 7;

    for (int kc = 0; kc < 16; ++kc) {
        S_VMCNT(0);               // K/V(kc) staged (issued a full step earlier)
        SCHED0(); SBAR(); SCHED0();
        if (kc < 15) { stage(kc + 1, (kc + 1) % 3); SCHED0(); }

        const unsigned short* Kc = &KsA[(kc % 3) * 4096];
        const unsigned short* Vc = &VsA[(kc % 3) * 4096];

        // QK per kf (32 keys) + softmax -> packed bf16 words aw[kf][0..7]
        unsigned aw[2][8];
#pragma unroll
        for (int kf = 0; kf < 2; ++kf) {
            f32x16 s;
#pragma unroll
            for (int i = 0; i < 16; i++) s[i] = 0.f;
            __builtin_amdgcn_s_setprio(1);
#pragma unroll
            for (int ks = 0; ks < 4; ++ks) {
                int row = kf * 32 + c;
                short8 kfr = *(const short8*)(Kc + row * 64 + (((ks << 1) | h) ^ c7) * 8);
                s = __builtin_amdgcn_mfma_f32_32x32x16_bf16(kfr, qf[ks], s, 0, 0, 0);
            }
            __builtin_amdgcn_s_setprio(0);
            // mask per reg-quad a: keys kf*32 + 8a + 4h + (0..3)
#pragma unroll
            for (int a = 0; a < 4; ++a) {
                float4 m4 = *(const float4*)(&mskf[kc * 64 + kf * 32 + a * 8 + h * 4]);
                float p0 = __builtin_amdgcn_exp2f(s[a * 4 + 0] * SC) * m4.x;
                float p1 = __builtin_amdgcn_exp2f(s[a * 4 + 1] * SC) * m4.y;
                float p2 = __builtin_amdgcn_exp2f(s[a * 4 + 2] * SC) * m4.z;
                float p3 = __builtin_amdgcn_exp2f(s[a * 4 + 3] * SC) * m4.w;
                aw[kf][a * 2 + 0] = cvtpk(p0, p1);
                aw[kf][a * 2 + 1] = cvtpk(p2, p3);
            }
        }

        // PV: 4 k-slices of 16 keys; A-fragments via permlane32_swap word pairs
#pragma unroll
        for (int t = 0; t < 4; ++t) {
            int kf = t >> 1, ib = (t & 1) * 4;
            unsigned u0 = aw[kf][ib + 0], v0 = aw[kf][ib + 2];
            unsigned u1 = aw[kf][ib + 1], v1 = aw[kf][ib + 3];
            asm volatile("v_permlane32_swap_b32 %0, %1" : "+v"(u0), "+v"(v0));
            asm volatile("v_permlane32_swap_b32 %0, %1" : "+v"(u1), "+v"(v1));
            union { unsigned u[4]; short8 s8; } pa;
            pa.u[0] = u0; pa.u[1] = u1; pa.u[2] = v0; pa.u[3] = v1;

            // V B-fragments: Vc[d=dblk*32+c][t*16 + h*8 + j]
            short8 vb0 = *(const short8*)(Vc + c * 64 + (((t << 1) | h) ^ c7) * 8);
            short8 vb1 = *(const short8*)(Vc + (32 + c) * 64 + (((t << 1) | h) ^ c7) * 8);
            __builtin_amdgcn_s_setprio(1);
            oacc0 = __builtin_amdgcn_mfma_f32_32x32x16_bf16(pa.s8, vb0, oacc0, 0, 0, 0);
            oacc1 = __builtin_amdgcn_mfma_f32_32x32x16_bf16(pa.s8, vb1, oacc1, 0, 0, 0);
            lacc  = __builtin_amdgcn_mfma_f32_32x32x16_bf16(pa.s8, ones8, lacc, 0, 0, 0);
            __builtin_amdgcn_s_setprio(0);
        }
    }

    // output: lane holds O[q=(reg&3)+8*(reg>>2)+4h][d=dblk*32+c], l in lacc[reg]
#pragma unroll
    for (int reg = 0; reg < 16; ++reg) {
        int q = (reg & 3) + 8 * (reg >> 2) + 4 * h;
        float inv = 1.0f / fmaxf(lacc[reg], 1e-30f);
        size_t rowbase = ((size_t)(b * 1024 + qt * 128 + wid * 32 + q)) * 768 + hh * 64 + c;
        O[rowbase]      = f2bf(oacc0[reg] * inv);
        O[rowbase + 32] = f2bf(oacc1[reg] * inv);
    }
}

// ---------------- launch ----------------
extern "C" void kernel_launch(void* const* d_in, const int* in_sizes, int n_in,
                              void* d_out, int out_size, void* d_ws, size_t ws_size,
                              hipStream_t stream)
{
    const float* x      = (const float*)d_in[0];
    const int*   mask   = (const int*)d_in[1];
    const float* g1     = (const float*)d_in[2];
    const float* b1     = (const float*)d_in[3];
    const float* w_qkv  = (const float*)d_in[4];
    const float* w_proj = (const float*)d_in[5];
    const float* b_proj = (const float*)d_in[6];
    const float* g2     = (const float*)d_in[7];
    const float* b2     = (const float*)d_in[8];
    const float* w_fc1  = (const float*)d_in[9];
    const float* b_fc1  = (const float*)d_in[10];
    const float* w_fc2  = (const float*)d_in[11];
    const float* b_fc2  = (const float*)d_in[12];
    float* out = (float*)d_out;

    char* ws = (char*)d_ws;
    unsigned short* wqkv_t  = (unsigned short*)(ws + 0);
    unsigned short* wproj_t = (unsigned short*)(ws + 3538944);
    unsigned short* wfc1_t  = (unsigned short*)(ws + 4718592);
    unsigned short* wfc2_t  = (unsigned short*)(ws + 5898240);
    unsigned short* bufA    = (unsigned short*)(ws + 7077888);   // h / h2
    unsigned short* bufB    = (unsigned short*)(ws + 19660800);  // o / gelu-out
    unsigned short* qb      = (unsigned short*)(ws + 32243712);
    unsigned short* kb      = (unsigned short*)(ws + 44826624);
    unsigned short* vtb     = (unsigned short*)(ws + 57409536);
    unsigned short* x1b     = (unsigned short*)(ws + 69992448);  // bf16 residual trunk
    unsigned short* xb      = (unsigned short*)(ws + 82575360);  // bf16 copy of x
    // total = 95,158,272 bytes

    k_prep<<<8192 + 3456, 256, 0, stream>>>(x, g1, b1, bufA, xb,
        w_qkv, w_proj, w_fc1, w_fc2, wqkv_t, wproj_t, wfc1_t, wfc2_t);

    k_gemm<0, 128><<<dim3(64, 18), 512, 0, stream>>>(bufA, wqkv_t,
        nullptr, nullptr, nullptr, nullptr, qb, kb, vtb);

    k_attn<<<dim3(8, 96), 256, 0, stream>>>(qb, kb, vtb, mask, bufB);

    k_gemm<1, 64><<<dim3(64, 12), 256, 0, stream>>>(bufB, wproj_t,
        b_proj, xb, nullptr, x1b, nullptr, nullptr, nullptr);

    k_layernorm_bf<<<8192, 256, 0, stream>>>(x1b, g2, b2, bufA);

    k_gemm<2, 64><<<dim3(64, 12), 256, 0, stream>>>(bufA, wfc1_t,
        b_fc1, nullptr, nullptr, bufB, nullptr, nullptr, nullptr);

    k_gemm<3, 64><<<dim3(64, 12), 256, 0, stream>>>(bufB, wfc2_t,
        b_fc2, x1b, out, nullptr, nullptr, nullptr, nullptr);
}

// Round 16
// 159.090 us; speedup vs baseline: 1.4948x; 1.0040x over previous
//
#include <hip/hip_runtime.h>
#include <stdint.h>
#include <math.h>

using short8 = __attribute__((ext_vector_type(8))) short;
using f32x4  = __attribute__((ext_vector_type(4))) float;
using f32x16 = __attribute__((ext_vector_type(16))) float;

#define DEV __device__ __forceinline__
#define S_VMCNT(n) asm volatile("s_waitcnt vmcnt(" #n ")" ::: "memory")
#define SCHED0()   __builtin_amdgcn_sched_barrier(0)
#define SBAR()     __builtin_amdgcn_s_barrier()

DEV unsigned short f2bf(float f) {
    union { float f; unsigned u; } c; c.f = f;
    unsigned u = c.u;
    unsigned r = (u + 0x7FFFu + ((u >> 16) & 1u)) >> 16;
    return (unsigned short)r;
}

DEV float bf2f(unsigned short h) {
    union { unsigned u; float f; } c; c.u = ((unsigned)h) << 16;
    return c.f;
}

DEV void gld16(const unsigned short* g, unsigned short* l) {
    __builtin_amdgcn_global_load_lds(
        (const __attribute__((address_space(1))) void*)g,
        (__attribute__((address_space(3))) void*)l, 16, 0, 0);
}

DEV unsigned cvtpk(float lo, float hi) {
    unsigned r;
    asm("v_cvt_pk_bf16_f32 %0, %1, %2" : "=v"(r) : "v"(lo), "v"(hi));
    return r;
}

// ---------------- prep: LN1 (+bf16 copy of x) fused with 4 weight transposes ----------------
__global__ __launch_bounds__(256) void k_prep(
    const float* __restrict__ x, const float* __restrict__ g,
    const float* __restrict__ b, unsigned short* __restrict__ h_out,
    unsigned short* __restrict__ xb,
    const float* __restrict__ w0, const float* __restrict__ w1,
    const float* __restrict__ w2, const float* __restrict__ w3,
    unsigned short* __restrict__ o0, unsigned short* __restrict__ o1,
    unsigned short* __restrict__ o2, unsigned short* __restrict__ o3)
{
    __shared__ float tile[32][33];
    __shared__ float red[8];
    int bid = blockIdx.x;
    int tid = threadIdx.x;

    if (bid < 8192) {
        int row = bid;
        const float* xr = x + (size_t)row * 768;
        float v0 = xr[tid], v1 = xr[tid + 256], v2 = xr[tid + 512];
        float s1 = v0 + v1 + v2;
        float s2 = v0 * v0 + v1 * v1 + v2 * v2;
#pragma unroll
        for (int off = 32; off >= 1; off >>= 1) {
            s1 += __shfl_down(s1, off);
            s2 += __shfl_down(s2, off);
        }
        int wid = tid >> 6, lane = tid & 63;
        if (lane == 0) { red[wid] = s1; red[4 + wid] = s2; }
        __syncthreads();
        s1 = red[0] + red[1] + red[2] + red[3];
        s2 = red[4] + red[5] + red[6] + red[7];
        float mu = s1 * (1.0f / 768.0f);
        float var = s2 * (1.0f / 768.0f) - mu * mu;
        float rs = rsqrtf(var + 1e-5f);
        unsigned short* orow = h_out + (size_t)row * 768;
        unsigned short* xrow = xb + (size_t)row * 768;
        orow[tid]       = f2bf((v0 - mu) * rs * g[tid]       + b[tid]);
        orow[tid + 256] = f2bf((v1 - mu) * rs * g[tid + 256] + b[tid + 256]);
        orow[tid + 512] = f2bf((v2 - mu) * rs * g[tid + 512] + b[tid + 512]);
        xrow[tid]       = f2bf(v0);
        xrow[tid + 256] = f2bf(v1);
        xrow[tid + 512] = f2bf(v2);
    } else {
        int idx = bid - 8192;
        const float* W; unsigned short* Wt; int N, n0, k0;
        if (idx < 1728) {
            W = w0; Wt = o0; N = 2304;
            n0 = (idx % 72) * 32; k0 = (idx / 72) * 32;
        } else {
            idx -= 1728;
            int z = idx / 576, r = idx % 576;
            W = (z == 0) ? w1 : (z == 1) ? w2 : w3;
            Wt = (z == 0) ? o1 : (z == 1) ? o2 : o3;
            N = 768;
            n0 = (r % 24) * 32; k0 = (r / 24) * 32;
        }
        int tx = tid & 31, ty = tid >> 5;
#pragma unroll
        for (int i = 0; i < 4; i++) {
            int k = k0 + ty + i * 8;
            tile[ty + i * 8][tx] = W[(size_t)k * N + n0 + tx];
        }
        __syncthreads();
#pragma unroll
        for (int i = 0; i < 4; i++) {
            int n = n0 + ty + i * 8;
            Wt[(size_t)n * 768 + k0 + tx] = f2bf(tile[tx][ty + i * 8]);
        }
    }
}

// ---------------- layernorm row(768) -> bf16; input bf16 ----------------
__global__ __launch_bounds__(256) void k_layernorm_bf(
    const unsigned short* __restrict__ xin, const float* __restrict__ g,
    const float* __restrict__ b, unsigned short* __restrict__ out)
{
    int row = blockIdx.x;
    int tid = threadIdx.x;
    const unsigned short* xr = xin + (size_t)row * 768;
    float v0 = bf2f(xr[tid]), v1 = bf2f(xr[tid + 256]), v2 = bf2f(xr[tid + 512]);
    float s1 = v0 + v1 + v2;
    float s2 = v0 * v0 + v1 * v1 + v2 * v2;
#pragma unroll
    for (int off = 32; off >= 1; off >>= 1) {
        s1 += __shfl_down(s1, off);
        s2 += __shfl_down(s2, off);
    }
    __shared__ float red[8];
    int wid = tid >> 6, lane = tid & 63;
    if (lane == 0) { red[wid] = s1; red[4 + wid] = s2; }
    __syncthreads();
    s1 = red[0] + red[1] + red[2] + red[3];
    s2 = red[4] + red[5] + red[6] + red[7];
    float mu = s1 * (1.0f / 768.0f);
    float var = s2 * (1.0f / 768.0f) - mu * mu;
    float rs = rsqrtf(var + 1e-5f);
    unsigned short* orow = out + (size_t)row * 768;
    orow[tid]       = f2bf((v0 - mu) * rs * g[tid]       + b[tid]);
    orow[tid + 256] = f2bf((v1 - mu) * rs * g[tid + 256] + b[tid + 256]);
    orow[tid + 512] = f2bf((v2 - mu) * rs * g[tid + 512] + b[tid + 512]);
}

// ---------------- GEMM (round-13 schedule): BK=64, 2 LDS bufs, counted vmcnt ----
// EPI 0: qkv scatter (q pre-scaled by 0.125*log2e; v via LDS transpose)
// EPI 1: proj(+bias+residH -> bf16)  2: fc1(+bias+gelu -> bf16)  3: fc2(+bias+residH -> f32)
template<int EPI, int BN>
__global__ __launch_bounds__(BN == 128 ? 512 : 256) void k_gemm(
    const unsigned short* __restrict__ A, const unsigned short* __restrict__ Bt,
    const float* __restrict__ bias, const unsigned short* __restrict__ residH,
    float* __restrict__ outF, unsigned short* __restrict__ outH,
    unsigned short* __restrict__ qb, unsigned short* __restrict__ kb,
    unsigned short* __restrict__ vtb)
{
    constexpr int KK = 768, NK = 12;
    constexpr int MI = 2;
    constexpr int NJ = 4;
    __shared__ __align__(16) unsigned short As[2][128 * 64];
    __shared__ __align__(16) unsigned short Bs[2][BN * 64];

    int tid = threadIdx.x;
    int lane = tid & 63, wid = tid >> 6;

    int gy = gridDim.y;
    int nwg = 64 * gy;
    int bid = blockIdx.x + blockIdx.y * 64;
    int nid = (bid & 7) * (nwg >> 3) + (bid >> 3);
    int bx = nid / gy;
    int by = nid - bx * gy;
    int m0 = bx * 128, n0 = by * BN;

    int wr = (BN == 128) ? (wid >> 1) * 32 : wid * 32;
    int wc = (BN == 128) ? (wid & 1) * 64 : 0;
    int fr = lane & 15, fg = lane >> 4;
    int fr7 = fr & 7;

    f32x4 zero4 = {0.f, 0.f, 0.f, 0.f};
    f32x4 acc[MI][NJ];
#pragma unroll
    for (int mi = 0; mi < MI; mi++)
#pragma unroll
        for (int nj = 0; nj < NJ; nj++) acc[mi][nj] = zero4;

    int srow = tid >> 3;
    int schk = (tid & 7) ^ ((tid >> 3) & 7);
    const unsigned short* ga = A  + (size_t)(m0 + srow) * KK + schk * 8;
    const unsigned short* gb = Bt + (size_t)(n0 + srow) * KK + schk * 8;

    auto stage = [&](int kt, int s) {
        int ko = kt * 64;
        if constexpr (BN == 128) {
            gld16(ga + ko, As[s] + wid * 512);
            gld16(ga + (size_t)64 * KK + ko, As[s] + 4096 + wid * 512);
            gld16(gb + ko, Bs[s] + wid * 512);
            gld16(gb + (size_t)64 * KK + ko, Bs[s] + 4096 + wid * 512);
        } else {
#pragma unroll
            for (int i = 0; i < 4; i++)
                gld16(ga + (size_t)i * 32 * KK + ko, As[s] + i * 2048 + wid * 512);
#pragma unroll
            for (int i = 0; i < 2; i++)
                gld16(gb + (size_t)i * 32 * KK + ko, Bs[s] + i * 2048 + wid * 512);
        }
    };

    int aoff0 = (wr + fr) * 64;
    int boff0 = (wc + fr) * 64;

    stage(0, 0);

    for (int k = 0; k < NK; ++k) {
        if (k + 1 < NK) {
            stage(k + 1, (k + 1) & 1);
            if constexpr (BN == 128) { S_VMCNT(4); } else { S_VMCNT(6); }
        } else {
            S_VMCNT(0);
        }
        SCHED0(); SBAR(); SCHED0();

        const unsigned short* Ac = As[k & 1];
        const unsigned short* Bc = Bs[k & 1];
#pragma unroll
        for (int kk = 0; kk < 2; ++kk) {
            int off = (((kk << 2) | fg) ^ fr7) * 8;
            short8 af[MI], bfv[NJ];
#pragma unroll
            for (int mi = 0; mi < MI; mi++)
                af[mi] = *(const short8*)(Ac + aoff0 + mi * 1024 + off);
#pragma unroll
            for (int nj = 0; nj < NJ; nj++)
                bfv[nj] = *(const short8*)(Bc + boff0 + nj * 1024 + off);
#pragma unroll
            for (int mi = 0; mi < MI; mi++)
#pragma unroll
                for (int nj = 0; nj < NJ; nj++)
                    acc[mi][nj] = __builtin_amdgcn_mfma_f32_16x16x32_bf16(
                        af[mi], bfv[nj], acc[mi][nj], 0, 0, 0);
        }
        SCHED0(); SBAR(); SCHED0();
    }

    if (EPI == 0 && n0 >= 1536) {
        unsigned short* Ct = &As[0][0];
#pragma unroll
        for (int mi = 0; mi < MI; mi++) {
#pragma unroll
            for (int nj = 0; nj < NJ; nj++) {
                int row = wc + nj * 16 + fr;
                int colb = wr + mi * 16 + fg * 4;
                int ch = (colb >> 3) ^ (row & 15);
                uint2 w;
                w.x = cvtpk(acc[mi][nj][0], acc[mi][nj][1]);
                w.y = cvtpk(acc[mi][nj][2], acc[mi][nj][3]);
                *(uint2*)(Ct + row * 128 + ch * 8 + (colb & 7)) = w;
            }
        }
        __syncthreads();
        int r = tid >> 2;
        int h0 = (n0 - 1536) >> 6;
        int bb = m0 >> 10;
        int nbase = m0 & 1023;
        size_t vbase = ((size_t)(bb * 12 + h0 + (r >> 6)) << 16)
                     + (size_t)(r & 63) * 1024 + nbase;
#pragma unroll
        for (int j = 0; j < 4; j++) {
            int c = (tid & 3) * 4 + j;
            int ch = c ^ (r & 15);
            uint4 v4 = *(const uint4*)(Ct + r * 128 + ch * 8);
            *(uint4*)(vtb + vbase + c * 8) = v4;
        }
        return;
    }

#pragma unroll
    for (int mi = 0; mi < MI; mi++) {
#pragma unroll
        for (int nj = 0; nj < NJ; nj++) {
#pragma unroll
            for (int i = 0; i < 4; i++) {
                int grow = m0 + wr + mi * 16 + fg * 4 + i;
                int gcol = n0 + wc + nj * 16 + fr;
                float v = acc[mi][nj][i];
                if (EPI == 0) {
                    int part = gcol / 768;
                    int wi = gcol - part * 768;
                    int head = wi >> 6, d = wi & 63;
                    int bb = grow >> 10, n = grow & 1023;
                    size_t base = ((size_t)(bb * 12 + head)) << 16;
                    if (part == 0) {
                        // pre-scale q by attn scale * log2(e): softmax becomes exp2(s+mask)
                        qb[base + (size_t)n * 64 + d] = f2bf(v * 0.18033688f);
                    } else {
                        kb[base + (size_t)n * 64 + d] = f2bf(v);
                    }
                } else if (EPI == 1) {
                    size_t idx = (size_t)grow * 768 + gcol;
                    outH[idx] = f2bf(v + bias[gcol] + bf2f(residH[idx]));
                } else if (EPI == 2) {
                    float t = v + bias[gcol];
                    outH[(size_t)grow * 768 + gcol] =
                        f2bf(0.5f * t * (1.0f + erff(t * 0.70710678118f)));
                } else {
                    size_t idx = (size_t)grow * 768 + gcol;
                    outF[idx] = v + bias[gcol] + bf2f(residH[idx]);
                }
            }
        }
    }
}

// ---------------- flash attention: 32x32 MFMA, in-register softmax (T12) ----------------
// Q pre-scaled by SC*log2e in qkv epilogue; mask additive in log2 domain
// (0 or -1e5 -> exp2 underflows to 0). p = exp2(s + m): one add+exp2 per elem.
__global__ __launch_bounds__(256) void k_attn(
    const unsigned short* __restrict__ Q, const unsigned short* __restrict__ Kk,
    const unsigned short* __restrict__ Vt, const int* __restrict__ mask,
    unsigned short* __restrict__ O)
{
    __shared__ __align__(16) unsigned short KsA[3 * 4096];
    __shared__ __align__(16) unsigned short VsA[3 * 4096];
    __shared__ __align__(16) float mskf[1024];

    int tid = threadIdx.x, lane = tid & 63, wid = tid >> 6;   // wid 0..3
    int bid = blockIdx.x + blockIdx.y * 8;
    int nid = (bid & 7) * 96 + (bid >> 3);
    int qt = nid & 7;          // 8 q-tiles of 128 rows
    int bh = nid >> 3;
    int b = bh / 12;
    int hh = bh - b * 12;
    int c = lane & 31, h = lane >> 5;

    const unsigned short* qg = Q  + ((size_t)bh << 16);
    const unsigned short* kg = Kk + ((size_t)bh << 16);
    const unsigned short* vg = Vt + ((size_t)bh << 16);

    for (int i = tid; i < 1024; i += 256)
        mskf[i] = mask[b * 1024 + i] ? 0.f : -1e5f;

    // Q B-fragments: qf[ks] = Q[q=qt*128+wid*32+c][ks*16 + h*8 .. +8]
    short8 qf[4];
    {
        const unsigned short* qp = qg + (size_t)(qt * 128 + wid * 32 + c) * 64 + h * 8;
#pragma unroll
        for (int ks = 0; ks < 4; ks++)
            qf[ks] = *(const short8*)(qp + ks * 16);
    }

    // staging: 256 thr, srow=tid>>3 covers 32 rows/issue; 2 issues per 64-row tile
    int srow = tid >> 3;
    int schk = (tid & 7) ^ (srow & 7);
    const unsigned short* kgp = kg + (size_t)srow * 64 + schk * 8;
    const unsigned short* vgp = vg + (size_t)srow * 1024 + schk * 8;

    auto stage = [&](int kn, int s) {
        unsigned short* Kd = &KsA[s * 4096];
        unsigned short* Vd = &VsA[s * 4096];
        gld16(kgp + (size_t)(kn * 64) * 64, Kd + wid * 512);
        gld16(kgp + (size_t)(kn * 64 + 32) * 64, Kd + 2048 + wid * 512);
        gld16(vgp + kn * 64, Vd + wid * 512);
        gld16(vgp + 32 * 1024 + kn * 64, Vd + 2048 + wid * 512);
    };

    stage(0, 0);
    __syncthreads();   // mskf + stage(0) drained (prologue only)

    f32x16 oacc0, oacc1, lacc;
#pragma unroll
    for (int i = 0; i < 16; i++) { oacc0[i] = 0.f; oacc1[i] = 0.f; lacc[i] = 0.f; }

    short8 ones8;
#pragma unroll
    for (int j = 0; j < 8; j++) ones8[j] = (short)0x3F80;   // bf16 1.0

    int c7 = c & 7;

    for (int kc = 0; kc < 16; ++kc) {
        S_VMCNT(0);               // K/V(kc) staged (issued a full step earlier)
        SCHED0(); SBAR(); SCHED0();
        if (kc < 15) { stage(kc + 1, (kc + 1) % 3); SCHED0(); }

        const unsigned short* Kc = &KsA[(kc % 3) * 4096];
        const unsigned short* Vc = &VsA[(kc % 3) * 4096];

        // QK per kf (32 keys) + softmax -> packed bf16 words aw[kf][0..7]
        unsigned aw[2][8];
#pragma unroll
        for (int kf = 0; kf < 2; ++kf) {
            f32x16 s;
#pragma unroll
            for (int i = 0; i < 16; i++) s[i] = 0.f;
            __builtin_amdgcn_s_setprio(1);
#pragma unroll
            for (int ks = 0; ks < 4; ++ks) {
                int row = kf * 32 + c;
                short8 kfr = *(const short8*)(Kc + row * 64 + (((ks << 1) | h) ^ c7) * 8);
                s = __builtin_amdgcn_mfma_f32_32x32x16_bf16(kfr, qf[ks], s, 0, 0, 0);
            }
            __builtin_amdgcn_s_setprio(0);
            // additive log2-mask per reg-quad a: keys kf*32 + 8a + 4h + (0..3)
#pragma unroll
            for (int a = 0; a < 4; ++a) {
                float4 m4 = *(const float4*)(&mskf[kc * 64 + kf * 32 + a * 8 + h * 4]);
                float p0 = __builtin_amdgcn_exp2f(s[a * 4 + 0] + m4.x);
                float p1 = __builtin_amdgcn_exp2f(s[a * 4 + 1] + m4.y);
                float p2 = __builtin_amdgcn_exp2f(s[a * 4 + 2] + m4.z);
                float p3 = __builtin_amdgcn_exp2f(s[a * 4 + 3] + m4.w);
                aw[kf][a * 2 + 0] = cvtpk(p0, p1);
                aw[kf][a * 2 + 1] = cvtpk(p2, p3);
            }
        }

        // PV: 4 k-slices of 16 keys; A-fragments via permlane32_swap word pairs
#pragma unroll
        for (int t = 0; t < 4; ++t) {
            int kf = t >> 1, ib = (t & 1) * 4;
            unsigned u0 = aw[kf][ib + 0], v0 = aw[kf][ib + 2];
            unsigned u1 = aw[kf][ib + 1], v1 = aw[kf][ib + 3];
            asm volatile("v_permlane32_swap_b32 %0, %1" : "+v"(u0), "+v"(v0));
            asm volatile("v_permlane32_swap_b32 %0, %1" : "+v"(u1), "+v"(v1));
            union { unsigned u[4]; short8 s8; } pa;
            pa.u[0] = u0; pa.u[1] = u1; pa.u[2] = v0; pa.u[3] = v1;

            // V B-fragments: Vc[d=dblk*32+c][t*16 + h*8 + j]
            short8 vb0 = *(const short8*)(Vc + c * 64 + (((t << 1) | h) ^ c7) * 8);
            short8 vb1 = *(const short8*)(Vc + (32 + c) * 64 + (((t << 1) | h) ^ c7) * 8);
            __builtin_amdgcn_s_setprio(1);
            oacc0 = __builtin_amdgcn_mfma_f32_32x32x16_bf16(pa.s8, vb0, oacc0, 0, 0, 0);
            oacc1 = __builtin_amdgcn_mfma_f32_32x32x16_bf16(pa.s8, vb1, oacc1, 0, 0, 0);
            lacc  = __builtin_amdgcn_mfma_f32_32x32x16_bf16(pa.s8, ones8, lacc, 0, 0, 0);
            __builtin_amdgcn_s_setprio(0);
        }
    }

    // output: lane holds O[q=(reg&3)+8*(reg>>2)+4h][d=dblk*32+c], l in lacc[reg]
#pragma unroll
    for (int reg = 0; reg < 16; ++reg) {
        int q = (reg & 3) + 8 * (reg >> 2) + 4 * h;
        float inv = 1.0f / fmaxf(lacc[reg], 1e-30f);
        size_t rowbase = ((size_t)(b * 1024 + qt * 128 + wid * 32 + q)) * 768 + hh * 64 + c;
        O[rowbase]      = f2bf(oacc0[reg] * inv);
        O[rowbase + 32] = f2bf(oacc1[reg] * inv);
    }
}

// ---------------- launch ----------------
extern "C" void kernel_launch(void* const* d_in, const int* in_sizes, int n_in,
                              void* d_out, int out_size, void* d_ws, size_t ws_size,
                              hipStream_t stream)
{
    const float* x      = (const float*)d_in[0];
    const int*   mask   = (const int*)d_in[1];
    const float* g1     = (const float*)d_in[2];
    const float* b1     = (const float*)d_in[3];
    const float* w_qkv  = (const float*)d_in[4];
    const float* w_proj = (const float*)d_in[5];
    const float* b_proj = (const float*)d_in[6];
    const float* g2     = (const float*)d_in[7];
    const float* b2     = (const float*)d_in[8];
    const float* w_fc1  = (const float*)d_in[9];
    const float* b_fc1  = (const float*)d_in[10];
    const float* w_fc2  = (const float*)d_in[11];
    const float* b_fc2  = (const float*)d_in[12];
    float* out = (float*)d_out;

    char* ws = (char*)d_ws;
    unsigned short* wqkv_t  = (unsigned short*)(ws + 0);
    unsigned short* wproj_t = (unsigned short*)(ws + 3538944);
    unsigned short* wfc1_t  = (unsigned short*)(ws + 4718592);
    unsigned short* wfc2_t  = (unsigned short*)(ws + 5898240);
    unsigned short* bufA    = (unsigned short*)(ws + 7077888);   // h / h2
    unsigned short* bufB    = (unsigned short*)(ws + 19660800);  // o / gelu-out
    unsigned short* qb      = (unsigned short*)(ws + 32243712);
    unsigned short* kb      = (unsigned short*)(ws + 44826624);
    unsigned short* vtb     = (unsigned short*)(ws + 57409536);
    unsigned short* x1b     = (unsigned short*)(ws + 69992448);  // bf16 residual trunk
    unsigned short* xb      = (unsigned short*)(ws + 82575360);  // bf16 copy of x
    // total = 95,158,272 bytes

    k_prep<<<8192 + 3456, 256, 0, stream>>>(x, g1, b1, bufA, xb,
        w_qkv, w_proj, w_fc1, w_fc2, wqkv_t, wproj_t, wfc1_t, wfc2_t);

    k_gemm<0, 128><<<dim3(64, 18), 512, 0, stream>>>(bufA, wqkv_t,
        nullptr, nullptr, nullptr, nullptr, qb, kb, vtb);

    k_attn<<<dim3(8, 96), 256, 0, stream>>>(qb, kb, vtb, mask, bufB);

    k_gemm<1, 64><<<dim3(64, 12), 256, 0, stream>>>(bufB, wproj_t,
        b_proj, xb, nullptr, x1b, nullptr, nullptr, nullptr);

    k_layernorm_bf<<<8192, 256, 0, stream>>>(x1b, g2, b2, bufA);

    k_gemm<2, 64><<<dim3(64, 12), 256, 0, stream>>>(bufA, wfc1_t,
        b_fc1, nullptr, nullptr, bufB, nullptr, nullptr, nullptr);

    k_gemm<3, 64><<<dim3(64, 12), 256, 0, stream>>>(bufB, wfc2_t,
        b_fc2, x1b, out, nullptr, nullptr, nullptr, nullptr);
}